// Round 4
// baseline (3222.318 us; speedup 1.0000x reference)
//
#include <hip/hip_runtime.h>
#include <stdint.h>

#define M_DIM 8192
#define K_DIM 4096
#define N_DIM 4096

using i32x4 = __attribute__((ext_vector_type(4))) int;
using i32x16 = __attribute__((ext_vector_type(16))) int;

typedef const __attribute__((address_space(1))) void g_void;
typedef __attribute__((address_space(3))) void lds_void;

__device__ __forceinline__ void gload_lds16(const void* g, void* l) {
  // async global->LDS, 16B/lane; LDS dest = wave-uniform base + lane*16
  __builtin_amdgcn_global_load_lds((g_void*)g, (lds_void*)l, 16, 0, 0);
}

__device__ __forceinline__ void barrier_raw() {
  asm volatile("" ::: "memory");
  __builtin_amdgcn_s_barrier();
  asm volatile("" ::: "memory");
}

__device__ __forceinline__ int sign4(float4 v) {
  int a = (v.x > 0.f) - (v.x < 0.f);
  int b = (v.y > 0.f) - (v.y < 0.f);
  int c = (v.z > 0.f) - (v.z < 0.f);
  int d = (v.w > 0.f) - (v.w < 0.f);
  return (a & 255) | ((b & 255) << 8) | ((c & 255) << 16) | ((d & 255) << 24);
}

// ---- pack x: fp32 [M][K] -> int8 sign [M][K] ----
__global__ void pack_x_kernel(const float* __restrict__ in,
                              int8_t* __restrict__ out, long n) {
  long i0 = ((long)blockIdx.x * blockDim.x + threadIdx.x) * 16;
  long stride = (long)gridDim.x * blockDim.x * 16;
  for (long i = i0; i < n; i += stride) {
    const float4* p = reinterpret_cast<const float4*>(in + i);
    i32x4 r;
    r.x = sign4(p[0]);
    r.y = sign4(p[1]);
    r.z = sign4(p[2]);
    r.w = sign4(p[3]);
    *reinterpret_cast<i32x4*>(out + i) = r;
  }
}

// ---- pack w: fp32 [K][N] -> int8 sign, TRANSPOSED to [N][K] ----
__global__ void pack_wt_kernel(const float* __restrict__ w,
                               int8_t* __restrict__ wt) {
  __shared__ int8_t tile[64 * 68];
  int n0 = blockIdx.x * 64;
  int k0 = blockIdx.y * 64;
  int t = threadIdx.x;
#pragma unroll
  for (int i = 0; i < 16; ++i) {
    int flat = t + 256 * i;
    int r = flat >> 6;          // k-local
    int c = flat & 63;          // n-local (coalesced)
    float v = w[(long)(k0 + r) * N_DIM + n0 + c];
    tile[c * 68 + r] = (int8_t)((v > 0.f) - (v < 0.f));
  }
  __syncthreads();
#pragma unroll
  for (int i = 0; i < 4; ++i) {
    int flat = t + 256 * i;
    int nn = flat >> 4;
    int kk = (flat & 15) << 2;
    int word = *reinterpret_cast<const int*>(&tile[nn * 68 + kk]);
    *reinterpret_cast<int*>(wt + (long)(n0 + nn) * K_DIM + k0 + kk) = word;
  }
}

// ---- i8 GEMM, 256x256 tile, BK=64, 8 waves (2Mx4N), mfma_i32_32x32x32_i8,
//      2 LDS buffers x 32KB = 64KB -> 2 blocks/CU, 1 barrier per tile ----
// Swizzle (both sides): LDS[row][c] = G[row][c ^ f(row)],
//   f(row) = ((row>>1)&3) ^ (((row>>4)&1)<<1)   (rows are 64B = 4 x 16B chunks)
// Stride-16 lane groups {i,i+16,i+32,i+48} now hit 4 distinct 16B slots
// (round-3's f lacked the bit4 term -> 1.26e7 conflicts).
__global__ __launch_bounds__(512, 4) void gemm_i8_kernel(
    const int8_t* __restrict__ A, const int8_t* __restrict__ B,
    float* __restrict__ C) {
  __shared__ __align__(16) int8_t lds[2 * 32768];  // 64 KiB

  // XCD-aware bijective swizzle: nwg = 512 = 8 * 64
  int bid = blockIdx.x;
  int wg = (bid & 7) * 64 + (bid >> 3);
  int bm = wg >> 4;  // M/256 = 32
  int bn = wg & 15;  // N/256 = 16

  int tid = threadIdx.x;
  int wid = tid >> 6;
  int lane = tid & 63;
  int wr = wid >> 2;  // 0..1 (M)
  int wc = wid & 3;   // 0..3 (N)

  const int8_t* Asrc = A + (long)bm * 256 * K_DIM;
  const int8_t* Bsrc = B + (long)bn * 256 * K_DIM;

  // staging: dst 16B-chunk index = tid (linear); row = tid>>2, c = tid&3.
  // src chunk = c ^ f(row); f bits from tid: (row>>1)&3 = (tid>>3)&3,
  // (row>>4)&1 = (tid>>6)&1
  int fst = ((tid >> 3) & 3) ^ (((tid >> 6) & 1) << 1);
  int srcChunk = ((tid & 3) ^ fst) << 4;
  long sOff0 = (long)(tid >> 2) * K_DIM + srcChunk;  // rows 0..127
  long sOff1 = sOff0 + 128L * K_DIM;                 // rows 128..255
  int dstOff = wid * 1024;  // wave-uniform; HW adds lane*16

  // frag reads: row = (lane&31), logical chunk c = q*2 + (lane>>5),
  // read chunk = c ^ f(row);  f = ((lane>>1)&3) ^ (((lane>>4)&1)<<1)
  int f = ((lane >> 1) & 3) ^ (((lane >> 4) & 1) << 1);
  int ck0 = ((lane >> 5) ^ f) << 4;  // q=0
  int ck1 = ck0 ^ 32;                // q=1 (c XOR 2)
  int aRd = (wr * 128 + (lane & 31)) * 64;
  int bRd = 16384 + (wc * 64 + (lane & 31)) * 64;

  i32x16 acc[4][2] = {};

  // prologue: stage tile 0 into buf0
  gload_lds16(Asrc + sOff0, lds + dstOff);
  gload_lds16(Asrc + sOff1, lds + 8192 + dstOff);
  gload_lds16(Bsrc + sOff0, lds + 16384 + dstOff);
  gload_lds16(Bsrc + sOff1, lds + 24576 + dstOff);
  asm volatile("s_waitcnt vmcnt(0)" ::: "memory");
  barrier_raw();

#pragma unroll 1
  for (int t = 0; t < 64; ++t) {
    const int8_t* buf = lds + (t & 1) * 32768;
    // issue next-tile staging FIRST (max issue->gate distance ~1 tile);
    // target buffer was last read at tile t-1, all reads retired before
    // the barrier we just passed (each wave's lgkmcnt(0) precedes it).
    if (t < 63) {
      long kn = (long)(t + 1) * 64;
      int8_t* nbuf = lds + ((t + 1) & 1) * 32768;
      gload_lds16(Asrc + sOff0 + kn, nbuf + dstOff);
      gload_lds16(Asrc + sOff1 + kn, nbuf + 8192 + dstOff);
      gload_lds16(Bsrc + sOff0 + kn, nbuf + 16384 + dstOff);
      gload_lds16(Bsrc + sOff1 + kn, nbuf + 24576 + dstOff);
    }
    // all 12 frag reads up front: q0 first (lgkm(6) retires exactly those)
    i32x4 af0[4], bf0[2], af1[4], bf1[2];
#pragma unroll
    for (int mi = 0; mi < 4; ++mi)
      af0[mi] = *reinterpret_cast<const i32x4*>(buf + aRd + mi * 2048 + ck0);
#pragma unroll
    for (int ni = 0; ni < 2; ++ni)
      bf0[ni] = *reinterpret_cast<const i32x4*>(buf + bRd + ni * 2048 + ck0);
#pragma unroll
    for (int mi = 0; mi < 4; ++mi)
      af1[mi] = *reinterpret_cast<const i32x4*>(buf + aRd + mi * 2048 + ck1);
#pragma unroll
    for (int ni = 0; ni < 2; ++ni)
      bf1[ni] = *reinterpret_cast<const i32x4*>(buf + bRd + ni * 2048 + ck1);
    asm volatile("s_waitcnt lgkmcnt(6)" ::: "memory");  // q0 ready, q1 in flight
    __builtin_amdgcn_sched_barrier(0);
    __builtin_amdgcn_s_setprio(1);
#pragma unroll
    for (int mi = 0; mi < 4; ++mi)
#pragma unroll
      for (int ni = 0; ni < 2; ++ni)
        acc[mi][ni] = __builtin_amdgcn_mfma_i32_32x32x32_i8(af0[mi], bf0[ni],
                                                            acc[mi][ni], 0, 0, 0);
    __builtin_amdgcn_s_setprio(0);
    asm volatile("s_waitcnt lgkmcnt(0)" ::: "memory");  // q1 ready
    __builtin_amdgcn_sched_barrier(0);
    __builtin_amdgcn_s_setprio(1);
#pragma unroll
    for (int mi = 0; mi < 4; ++mi)
#pragma unroll
      for (int ni = 0; ni < 2; ++ni)
        acc[mi][ni] = __builtin_amdgcn_mfma_i32_32x32x32_i8(af1[mi], bf1[ni],
                                                            acc[mi][ni], 0, 0, 0);
    __builtin_amdgcn_s_setprio(0);
    // gate: next tile's staging landed; single barrier per tile
    asm volatile("s_waitcnt vmcnt(0)" ::: "memory");
    barrier_raw();
  }

  // C/D 32x32 layout: col = lane&31, row = (reg&3) + 8*(reg>>2) + 4*(lane>>5)
  long row0 = (long)bm * 256 + wr * 128 + ((lane >> 5) << 2);
  long col0 = (long)bn * 256 + wc * 64 + (lane & 31);
#pragma unroll
  for (int mi = 0; mi < 4; ++mi)
#pragma unroll
    for (int ni = 0; ni < 2; ++ni)
#pragma unroll
      for (int r = 0; r < 16; ++r) {
        long row = row0 + mi * 32 + (r & 3) + ((r >> 2) << 3);
        C[row * N_DIM + col0 + ni * 32] = (float)acc[mi][ni][r];
      }
}

extern "C" void kernel_launch(void* const* d_in, const int* in_sizes, int n_in,
                              void* d_out, int out_size, void* d_ws, size_t ws_size,
                              hipStream_t stream) {
  const float* x = (const float*)d_in[0];
  const float* w = (const float*)d_in[1];
  float* out = (float*)d_out;

  int8_t* xb = (int8_t*)d_ws;                // 32 MB: sign(x) [M][K]
  int8_t* wbt = xb + (size_t)M_DIM * K_DIM;  // 16 MB: sign(w)^T [N][K]

  pack_x_kernel<<<2048, 256, 0, stream>>>(x, xb, (long)M_DIM * K_DIM);
  pack_wt_kernel<<<dim3(N_DIM / 64, K_DIM / 64), 256, 0, stream>>>(w, wbt);
  gemm_i8_kernel<<<512, 512, 0, stream>>>(xb, wbt, out);
}

// Round 5
// 177.872 us; speedup vs baseline: 18.1159x; 18.1159x over previous
//
#include <hip/hip_runtime.h>
#include <stdint.h>

#define M_DIM 8192
#define K_DIM 4096
#define N_DIM 4096

using i32x4 = __attribute__((ext_vector_type(4))) int;

typedef const __attribute__((address_space(1))) void g_void;
typedef __attribute__((address_space(3))) void lds_void;

__device__ __forceinline__ void gload_lds16(const void* g, void* l) {
  // async global->LDS, 16B/lane; LDS dest = wave-uniform base + lane*16
  __builtin_amdgcn_global_load_lds((g_void*)g, (lds_void*)l, 16, 0, 0);
}

__device__ __forceinline__ void barrier_raw() {
  asm volatile("" ::: "memory");
  __builtin_amdgcn_s_barrier();
  asm volatile("" ::: "memory");
}

__device__ __forceinline__ int sign4(float4 v) {
  int a = (v.x > 0.f) - (v.x < 0.f);
  int b = (v.y > 0.f) - (v.y < 0.f);
  int c = (v.z > 0.f) - (v.z < 0.f);
  int d = (v.w > 0.f) - (v.w < 0.f);
  return (a & 255) | ((b & 255) << 8) | ((c & 255) << 16) | ((d & 255) << 24);
}

// ---- pack x: fp32 [M][K] -> int8 sign [M][K] ----
__global__ void pack_x_kernel(const float* __restrict__ in,
                              int8_t* __restrict__ out, long n) {
  long i0 = ((long)blockIdx.x * blockDim.x + threadIdx.x) * 16;
  long stride = (long)gridDim.x * blockDim.x * 16;
  for (long i = i0; i < n; i += stride) {
    const float4* p = reinterpret_cast<const float4*>(in + i);
    i32x4 r;
    r.x = sign4(p[0]);
    r.y = sign4(p[1]);
    r.z = sign4(p[2]);
    r.w = sign4(p[3]);
    *reinterpret_cast<i32x4*>(out + i) = r;
  }
}

// ---- pack w: fp32 [K][N] -> int8 sign, TRANSPOSED to [N][K] ----
__global__ void pack_wt_kernel(const float* __restrict__ w,
                               int8_t* __restrict__ wt) {
  __shared__ int8_t tile[64 * 68];
  int n0 = blockIdx.x * 64;
  int k0 = blockIdx.y * 64;
  int t = threadIdx.x;
#pragma unroll
  for (int i = 0; i < 16; ++i) {
    int flat = t + 256 * i;
    int r = flat >> 6;          // k-local
    int c = flat & 63;          // n-local (coalesced)
    float v = w[(long)(k0 + r) * N_DIM + n0 + c];
    tile[c * 68 + r] = (int8_t)((v > 0.f) - (v < 0.f));
  }
  __syncthreads();
#pragma unroll
  for (int i = 0; i < 4; ++i) {
    int flat = t + 256 * i;
    int nn = flat >> 4;
    int kk = (flat & 15) << 2;
    int word = *reinterpret_cast<const int*>(&tile[nn * 68 + kk]);
    *reinterpret_cast<int*>(wt + (long)(n0 + nn) * K_DIM + k0 + kk) = word;
  }
}

// ---- i8 GEMM: 256x256 tile, BK=64, 8 waves (2Mx4N), mfma_i32_16x16x64_i8,
//      round-2's ZERO-conflict LDS layout + fully-counted 1-barrier/tile
//      register-ping-pong pipeline, 4-deep LDS buffers (128 KiB, 1 block/CU).
// Layout (measured 0 bank conflicts in R2): LDS[row][c] = G[row][c ^ f(row)],
//   f(row) = (row>>1)&3 (rows = 64 B = 4 x 16B chunks); frag reads use
//   row = base + (lane&15), chunk = (lane>>4) ^ f.
// Hazard ledger (1 barrier/tile): all LDS reads of tile t retire (counted
// lgkm) BEFORE tile t's vm-barrier; staging into slot t&3 re-issues at tile
// t+1 ph0, i.e. after that barrier -> race-free across waves.
template <int VM, bool ISSUE, bool READ_NEXT>
__device__ __forceinline__ void tile_step(
    int t, const int8_t* __restrict__ Asrc, const int8_t* __restrict__ Bsrc,
    long sOff0, long sOff1, int dstOff, int8_t* lds, int aRd, int bRd,
    i32x4 (&afC)[4], i32x4 (&bfC)[4], i32x4 (&afN)[4], i32x4 (&bfN)[4],
    i32x4 (&afH)[4], i32x4 (&acc)[8][4]) {
  const int8_t* buf = lds + (t & 3) * 32768;
  // ---------------- phase 0 ----------------
  // issue af4-7 of tile t (drain under this phase's MFMAs)
#pragma unroll
  for (int m = 0; m < 4; ++m)
    afH[m] = *reinterpret_cast<const i32x4*>(buf + aRd + (4 + m) * 1024);
  if (ISSUE) {
    long kn = (long)(t + 3) * 64;
    int8_t* nbuf = lds + ((t + 3) & 3) * 32768;
    gload_lds16(Asrc + sOff0 + kn, nbuf + dstOff);
    gload_lds16(Asrc + sOff1 + kn, nbuf + 8192 + dstOff);
  }
  // retire the 8 regA reads (issued last tile); afH stays in flight
  asm volatile("s_waitcnt lgkmcnt(4)" ::: "memory");
  __builtin_amdgcn_sched_barrier(0);
  __builtin_amdgcn_s_setprio(1);
#pragma unroll
  for (int m = 0; m < 4; ++m)
#pragma unroll
    for (int n = 0; n < 4; ++n)
      acc[m][n] = __builtin_amdgcn_mfma_i32_16x16x64_i8(afC[m], bfC[n],
                                                        acc[m][n], 0, 0, 0);
  __builtin_amdgcn_s_setprio(0);
  // ---------------- phase 1 ----------------
  asm volatile("s_waitcnt lgkmcnt(0)" ::: "memory");  // afH ready
  __builtin_amdgcn_sched_barrier(0);
  if (ISSUE) {
    long kn = (long)(t + 3) * 64;
    int8_t* nbuf = lds + ((t + 3) & 3) * 32768;
    gload_lds16(Bsrc + sOff0 + kn, nbuf + 16384 + dstOff);
    gload_lds16(Bsrc + sOff1 + kn, nbuf + 24576 + dstOff);
  }
  if (VM >= 0) {  // vm-gate: tile t+1 fully landed, all waves past it
    if (VM == 8) asm volatile("s_waitcnt vmcnt(8)" ::: "memory");
    else if (VM == 4) asm volatile("s_waitcnt vmcnt(4)" ::: "memory");
    else asm volatile("s_waitcnt vmcnt(0)" ::: "memory");
    barrier_raw();
  }
  if (READ_NEXT) {  // issue regA of tile t+1 (drain under ph1 MFMAs)
    const int8_t* nrbuf = lds + ((t + 1) & 3) * 32768;
#pragma unroll
    for (int m = 0; m < 4; ++m)
      afN[m] = *reinterpret_cast<const i32x4*>(nrbuf + aRd + m * 1024);
#pragma unroll
    for (int n = 0; n < 4; ++n)
      bfN[n] = *reinterpret_cast<const i32x4*>(nrbuf + bRd + n * 1024);
  }
  __builtin_amdgcn_s_setprio(1);
#pragma unroll
  for (int m = 0; m < 4; ++m)
#pragma unroll
    for (int n = 0; n < 4; ++n)
      acc[4 + m][n] = __builtin_amdgcn_mfma_i32_16x16x64_i8(afH[m], bfC[n],
                                                            acc[4 + m][n], 0, 0, 0);
  __builtin_amdgcn_s_setprio(0);
}

__global__ __launch_bounds__(512, 2) void gemm_i8_kernel(
    const int8_t* __restrict__ A, const int8_t* __restrict__ B,
    float* __restrict__ C) {
  __shared__ __align__(16) int8_t lds[4 * 32768];  // 128 KiB

  // XCD-aware bijective swizzle: nwg = 512 = 8 * 64
  int bid = blockIdx.x;
  int wg = (bid & 7) * 64 + (bid >> 3);
  int bm = wg >> 4;  // M/256 = 32
  int bn = wg & 15;  // N/256 = 16

  int tid = threadIdx.x;
  int wid = tid >> 6;
  int lane = tid & 63;
  int wr = wid >> 2;  // 0..1 (M)
  int wc = wid & 3;   // 0..3 (N)

  const int8_t* Asrc = A + (long)bm * 256 * K_DIM;
  const int8_t* Bsrc = B + (long)bn * 256 * K_DIM;

  // staging (R2-proven): dst chunk = tid; row = tid>>2, c = tid&3;
  // src chunk = (tid&3) ^ ((row>>1)&3) = (tid&3) ^ ((tid>>3)&3)
  int srcChunk = ((tid & 3) ^ ((tid >> 3) & 3)) << 4;
  long sOff0 = (long)(tid >> 2) * K_DIM + srcChunk;  // rows 0..127
  long sOff1 = sOff0 + 128L * K_DIM;                 // rows 128..255
  int dstOff = wid * 1024;  // wave-uniform; HW adds lane*16

  // frag reads (R2-proven, 0 conflicts): row = W + m*16 + (lane&15),
  // chunk = (lane>>4) ^ f(row), f = ((lane&15)>>1)&3
  int rswz = ((lane >> 4) ^ (((lane & 15) >> 1) & 3)) << 4;
  int aRd = (wr * 128 + (lane & 15)) * 64 + rswz;
  int bRd = 16384 + (wc * 64 + (lane & 15)) * 64 + rswz;

  i32x4 afA[4], bfA[4], afB[4], bfB[4], afH[4];
  i32x4 acc[8][4] = {};

  // prologue: stage tiles 0,1,2
#pragma unroll
  for (int t = 0; t < 3; ++t) {
    int8_t* buf = lds + t * 32768;
    long k0 = (long)t * 64;
    gload_lds16(Asrc + sOff0 + k0, buf + dstOff);
    gload_lds16(Asrc + sOff1 + k0, buf + 8192 + dstOff);
    gload_lds16(Bsrc + sOff0 + k0, buf + 16384 + dstOff);
    gload_lds16(Bsrc + sOff1 + k0, buf + 24576 + dstOff);
  }
  asm volatile("s_waitcnt vmcnt(8)" ::: "memory");  // tile 0 landed
  barrier_raw();
  // issue regA of tile 0 (retired by tile-0 ph0's lgkmcnt(4))
#pragma unroll
  for (int m = 0; m < 4; ++m)
    afA[m] = *reinterpret_cast<const i32x4*>(lds + aRd + m * 1024);
#pragma unroll
  for (int n = 0; n < 4; ++n)
    bfA[n] = *reinterpret_cast<const i32x4*>(lds + bRd + n * 1024);

#pragma unroll 1
  for (int tt = 0; tt < 60; tt += 2) {
    tile_step<8, true, true>(tt, Asrc, Bsrc, sOff0, sOff1, dstOff, lds, aRd,
                             bRd, afA, bfA, afB, bfB, afH, acc);
    tile_step<8, true, true>(tt + 1, Asrc, Bsrc, sOff0, sOff1, dstOff, lds,
                             aRd, bRd, afB, bfB, afA, bfA, afH, acc);
  }
  tile_step<8, true, true>(60, Asrc, Bsrc, sOff0, sOff1, dstOff, lds, aRd, bRd,
                           afA, bfA, afB, bfB, afH, acc);
  tile_step<4, false, true>(61, Asrc, Bsrc, sOff0, sOff1, dstOff, lds, aRd,
                            bRd, afB, bfB, afA, bfA, afH, acc);
  tile_step<0, false, true>(62, Asrc, Bsrc, sOff0, sOff1, dstOff, lds, aRd,
                            bRd, afA, bfA, afB, bfB, afH, acc);
  tile_step<-1, false, false>(63, Asrc, Bsrc, sOff0, sOff1, dstOff, lds, aRd,
                              bRd, afB, bfB, afA, bfA, afH, acc);

  // C/D 16x16 layout: col = lane&15, row = (lane>>4)*4 + reg
  long row0 = (long)bm * 256 + wr * 128 + ((lane >> 4) << 2);
  long col0 = (long)bn * 256 + wc * 64 + (lane & 15);
#pragma unroll
  for (int m = 0; m < 8; ++m)
#pragma unroll
    for (int n = 0; n < 4; ++n)
#pragma unroll
      for (int r = 0; r < 4; ++r)
        C[(row0 + m * 16 + r) * N_DIM + col0 + n * 16] = (float)acc[m][n][r];
}

extern "C" void kernel_launch(void* const* d_in, const int* in_sizes, int n_in,
                              void* d_out, int out_size, void* d_ws, size_t ws_size,
                              hipStream_t stream) {
  const float* x = (const float*)d_in[0];
  const float* w = (const float*)d_in[1];
  float* out = (float*)d_out;

  int8_t* xb = (int8_t*)d_ws;                // 32 MB: sign(x) [M][K]
  int8_t* wbt = xb + (size_t)M_DIM * K_DIM;  // 16 MB: sign(w)^T [N][K]

  pack_x_kernel<<<2048, 256, 0, stream>>>(x, xb, (long)M_DIM * K_DIM);
  pack_wt_kernel<<<dim3(N_DIM / 64, K_DIM / 64), 256, 0, stream>>>(w, wbt);
  gemm_i8_kernel<<<512, 512, 0, stream>>>(xb, wbt, out);
}